// Round 8
// baseline (3879.188 us; speedup 1.0000x reference)
//
#include <hip/hip_runtime.h>
#include <hip/hip_fp16.h>

// Problem sizes
#define B_SZ 32
#define L_SZ 512
#define D_SZ 1024
#define H_SZ 1024
#define NG   4096           // 4*H
#define M_SZ 16384          // B*L

typedef __attribute__((ext_vector_type(8))) short short8;
typedef __attribute__((ext_vector_type(4))) float f32x4;
typedef __attribute__((ext_vector_type(4))) unsigned u32x4;
typedef __attribute__((ext_vector_type(4))) unsigned short u16x4;

// Workspace layout (bytes). Total ~184.7 MB.
// XB region doubles as the h RING (512 slots x 64 KB = exactly 32 MiB) once
// k_xgemm has consumed the bf16 x data. Slot t holds h_t as fp16(h+2)
// (values in (1,3) -> every ushort >= 0x3C00, never 0). Slots 1..511 are
// pre-zeroed each launch, so dword==0 <=> not yet written.
static const size_t GX_OFF  = 0;                  // Gx fp16: 16384*4096*2 = 134217728
static const size_t XB_OFF  = 134217728;          // x bf16 / h ring: 33554432
static const size_t WH_OFF  = 167772160;          // Wh bf16: 8388608
static const size_t WX_OFF  = 176160768;          // Wx bf16: 8388608

__device__ __forceinline__ unsigned short f2bf(float f) {
  union { float f; unsigned u; } v; v.f = f;
  unsigned r = v.u + 0x7fffu + ((v.u >> 16) & 1u);
  return (unsigned short)(r >> 16);
}

__device__ __forceinline__ void gload_lds16(const void* g, void* l) {
  __builtin_amdgcn_global_load_lds(
      (const __attribute__((address_space(1))) unsigned*)g,
      (__attribute__((address_space(3))) unsigned*)l, 16, 0, 0);
}

// ---- prep kernels -----------------------------------------------------------

__global__ __launch_bounds__(256) void k_convert_w(const float* __restrict__ W,
                                                   unsigned short* __restrict__ Wh,
                                                   unsigned short* __restrict__ Wx) {
  int idx = blockIdx.x * 256 + threadIdx.x;          // 4096*2048/4 = 2097152 total
  f32x4 v = ((const f32x4*)W)[idx];
  u16x4 o;
#pragma unroll
  for (int e = 0; e < 4; ++e) o[e] = f2bf(v[e]);
  int n   = idx >> 9;                                // 512 float4 per 2048-col row
  int col = (idx & 511) * 4;
  if (col < 1024) *(u16x4*)(Wh + (size_t)n * 1024 + col)          = o;
  else            *(u16x4*)(Wx + (size_t)n * 1024 + (col - 1024)) = o;
}

// xb region later becomes the h ring, written sc0sc1 (write-through). xb is
// also stored write-through so NO dirty L2 line of this region can ever be
// written back late and clobber ring data.
__global__ __launch_bounds__(256) void k_convert_x(const float* __restrict__ x,
                                                   unsigned short* __restrict__ xb) {
  int idx = blockIdx.x * 256 + threadIdx.x;          // 16777216/4 = 4194304 total
  f32x4 v = ((const f32x4*)x)[idx];
  u16x4 o;
#pragma unroll
  for (int e = 0; e < 4; ++e) o[e] = f2bf(v[e]);
  unsigned long long val;
  __builtin_memcpy(&val, &o, 8);
  unsigned short* p = xb + (size_t)idx * 4;
  asm volatile("global_store_dwordx2 %0, %1, off sc0 sc1"
               :: "v"(p), "v"(val) : "memory");
}

__global__ __launch_bounds__(256) void k_zero_wt(unsigned* __restrict__ p, int n) {
  int i = blockIdx.x * 256 + threadIdx.x;
  unsigned z = 0u;
  if (i < n)
    asm volatile("global_store_dword %0, %1, off sc0 sc1"
                 :: "v"(p + i), "v"(z) : "memory");
}

// ---- x-projection GEMM: Gx[m][n] = sum_d x[m][d] * Wx[n][d] (fp16 out) ------

__global__ __launch_bounds__(256) void k_xgemm(const unsigned short* __restrict__ A,
                                               const unsigned short* __restrict__ Bw,
                                               __half* __restrict__ C) {
  __shared__ unsigned short sA[128 * 64];
  __shared__ unsigned short sB[128 * 64];
  const int m0 = blockIdx.x * 128;
  const int n0 = blockIdx.y * 128;
  const int tid = threadIdx.x;
  const int lane = tid & 63;
  const int w = tid >> 6;
  const int wm = w >> 1, wn = w & 1;
  f32x4 acc[4][4] = {};
  for (int k0 = 0; k0 < 1024; k0 += 64) {
#pragma unroll
    for (int it = 0; it < 4; ++it) {
      int chunk = it * 256 + w * 64 + lane;
      int row = chunk >> 3, kc = chunk & 7;
      gload_lds16(A + (size_t)(m0 + row) * 1024 + k0 + kc * 8,
                  (char*)sA + (size_t)(it * 256 + w * 64) * 16);
      gload_lds16(Bw + (size_t)(n0 + row) * 1024 + k0 + kc * 8,
                  (char*)sB + (size_t)(it * 256 + w * 64) * 16);
    }
    asm volatile("s_waitcnt vmcnt(0)" ::: "memory");
    __syncthreads();
#pragma unroll
    for (int ks = 0; ks < 2; ++ks) {
      short8 af[4], bfr[4];
#pragma unroll
      for (int i = 0; i < 4; ++i) {
        int arow = wm * 64 + i * 16 + (lane & 15);
        af[i] = *(const short8*)(sA + arow * 64 + ks * 32 + (lane >> 4) * 8);
      }
#pragma unroll
      for (int j = 0; j < 4; ++j) {
        int brow = wn * 64 + j * 16 + (lane & 15);
        bfr[j] = *(const short8*)(sB + brow * 64 + ks * 32 + (lane >> 4) * 8);
      }
#pragma unroll
      for (int i = 0; i < 4; ++i)
#pragma unroll
        for (int j = 0; j < 4; ++j)
          acc[i][j] = __builtin_amdgcn_mfma_f32_16x16x32_bf16(af[i], bfr[j], acc[i][j], 0, 0, 0);
    }
    __syncthreads();
  }
#pragma unroll
  for (int i = 0; i < 4; ++i)
#pragma unroll
    for (int j = 0; j < 4; ++j)
#pragma unroll
      for (int q = 0; q < 4; ++q) {
        int row = m0 + wm * 64 + i * 16 + (lane >> 4) * 4 + q;
        int col = n0 + wn * 64 + j * 16 + (lane & 15);
        C[(size_t)row * NG + col] = __float2half(acc[i][j][q]);
      }
}

// ---- persistent recurrent kernel -------------------------------------------
// 128 WGs x 256 threads (1 WG/CU -> co-resident). WG wg owns hidden j0..j0+7
// across all 4 gates (32 gate columns). Wh slice + h_t in XOR-swizzled LDS.
//
// SYNC-FREE tagged ring: producers fire-and-forget sc0sc1 16B stores of
// fp16(h+2) into virgin (pre-zeroed) slot t+1. Consumers load slot t with
// sc0sc1 (cache-bypassing - REQUIRED: a cached stale-zero L2 copy would spin
// forever) and retry each 16B chunk until all 4 dwords are nonzero (fresh
// halves are >= 0x3C00, stale are 0x0000; dword writes are atomic). The poll
// IS the fetch: no flags, no store-drain, no global barrier. Lockstep
// emerges from the data dependency. Decode h'-2 is EXACT in fp16.

__global__ __launch_bounds__(256) void k_lstm(const unsigned short* __restrict__ Whg,
                                              const __half* __restrict__ Gx,
                                              const float* __restrict__ bias,
                                              unsigned short* __restrict__ ring,
                                              float* __restrict__ out) {
  extern __shared__ char lds[];
  char* w_base = lds;                               // 65536 B, swizzled [32][1024] bf16
  char* h_base = lds + 65536;                       // 65536 B, swizzled [32][1024] bf16
  float* gates_s = (float*)(lds + 131072);          // [32][33] fp32
  float* bias_s  = (float*)(lds + 131072 + 4224);   // [32]
  unsigned short* hlds = (unsigned short*)(lds + 131072 + 4224 + 128); // [256] fp16(h+2)

  const int tid = threadIdx.x;
  const int lane = tid & 63;
  const int w = tid >> 6;
  const int wg = blockIdx.x;
  const int j0 = wg * 8;

  // Stage Wh slice once: local col c (0..31) -> global gate row (c>>3)*1024 + j0 + (c&7)
  for (int i = tid; i < 4096; i += 256) {           // 32 rows * 128 16B-chunks
    int c = i >> 7, kc = i & 127;
    int n = (c >> 3) * 1024 + j0 + (c & 7);
    u32x4 v = *(const u32x4*)(Whg + (size_t)n * 1024 + kc * 8);
    *(u32x4*)(w_base + c * 2048 + ((kc * 16) ^ ((c & 7) << 4))) = v;
  }
  if (tid < 32) bias_s[tid] = bias[(tid >> 3) * 1024 + j0 + (tid & 7)];
  __syncthreads();

  const int mt = w >> 1, nt = w & 1;
  const int arow = mt * 16 + (lane & 15);
  const int brow = nt * 16 + (lane & 15);
  const char* aBase = h_base + arow * 2048;
  const char* bBase = w_base + brow * 2048;
  const int kslot = (lane >> 4) * 16;
  const int aswz = (arow & 7) << 4;
  const int bswz = (brow & 7) << 4;
  const int b_ = tid >> 3, jj = tid & 7;
  const float rb0 = bias_s[jj], rb1 = bias_s[8 + jj];
  const float rb2 = bias_s[16 + jj], rb3 = bias_s[24 + jj];
  const __half2 two2 = __floats2half2_rn(2.f, 2.f);
  float c_reg = 0.f;                                // cell state (thread-private)

  for (int t = 0; t < 512; ++t) {
    const char* hin = (const char*)ring + (size_t)t * 65536;         // slot t
    unsigned short* hout = ring + (size_t)(t + 1) * 32768;           // slot t+1

    // ---- issue Gx loads first (cached; drained by retry vmcnt(0)) ----
    const char* gxp = (const char*)(Gx + ((size_t)(b_ * L_SZ + t)) * NG + j0 + jj);
    unsigned gxa, gxb, gxc, gxd;
    asm volatile("global_load_ushort %0, %1, off" : "=v"(gxa) : "v"(gxp)        : "memory");
    asm volatile("global_load_ushort %0, %1, off" : "=v"(gxb) : "v"(gxp + 2048) : "memory");
    asm volatile("global_load_ushort %0, %1, off" : "=v"(gxc) : "v"(gxp + 4096) : "memory");
    asm volatile("global_load_ushort %0, %1, off" : "=v"(gxd) : "v"(gxp + 6144) : "memory");

    // ---- tagged-data retry fetch + decode + swizzled LDS stage ----
    if (t) {
      u32x4 hr[16];
      unsigned ready = 0;
#define HISSUE(it) \
      if (!(ready & (1u << (it)))) \
        asm volatile("global_load_dwordx4 %0, %1, off sc0 sc1" \
            : "=v"(hr[it]) : "v"(hin + (size_t)((it) * 256 + tid) * 16) : "memory")
#pragma unroll
      for (int it = 0; it < 16; ++it) HISSUE(it);
      for (;;) {
        asm volatile("s_waitcnt vmcnt(0)" ::: "memory");
#pragma unroll
        for (int it = 0; it < 16; ++it) {
          if (!(ready & (1u << it))) {
            u32x4 d = hr[it];
            if (d[0] && d[1] && d[2] && d[3]) {      // fresh (all dwords nonzero)
              u32x4 o;
#pragma unroll
              for (int k2 = 0; k2 < 4; ++k2) {       // fp16(h+2) -> bf16(h)
                unsigned dv = d[k2];
                __half2 hh;
                __builtin_memcpy(&hh, &dv, 4);
                __half2 r = __hsub2(hh, two2);       // exact
                float f0 = __half2float(__low2half(r));
                float f1 = __half2float(__high2half(r));
                unsigned w_;
                asm("v_cvt_pk_bf16_f32 %0, %1, %2" : "=v"(w_) : "v"(f0), "v"(f1));
                o[k2] = w_;
              }
              int i_ = it * 256 + tid;
              int bb_ = i_ >> 7, kc_ = i_ & 127;
              *(u32x4*)(h_base + bb_ * 2048 + ((kc_ * 16) ^ ((bb_ & 7) << 4))) = o;
              ready |= (1u << it);
            }
          }
        }
        if (ready == 0xFFFFu) break;
#pragma unroll
        for (int it = 0; it < 16; ++it) HISSUE(it);  // re-issue stale chunks
      }
#undef HISSUE
    } else {
      u32x4 z = {0u, 0u, 0u, 0u};
#pragma unroll
      for (int it = 0; it < 16; ++it) {
        int i_ = it * 256 + tid;
        int bb_ = i_ >> 7, kc_ = i_ & 127;
        *(u32x4*)(h_base + bb_ * 2048 + ((kc_ * 16) ^ ((bb_ & 7) << 4))) = z;
      }
    }
    __syncthreads();

    // ---- gates(32x32) = h_t @ Wh_slice^T (each wave: one 16x16 quadrant) ----
    f32x4 acc0 = {0.f, 0.f, 0.f, 0.f}, acc1 = {0.f, 0.f, 0.f, 0.f};
#pragma unroll
    for (int ks = 0; ks < 32; ks += 2) {
      short8 a0 = *(const short8*)(aBase + (((ks)     * 64 + kslot) ^ aswz));
      short8 a1 = *(const short8*)(aBase + (((ks + 1) * 64 + kslot) ^ aswz));
      short8 b0 = *(const short8*)(bBase + (((ks)     * 64 + kslot) ^ bswz));
      short8 b1 = *(const short8*)(bBase + (((ks + 1) * 64 + kslot) ^ bswz));
      acc0 = __builtin_amdgcn_mfma_f32_16x16x32_bf16(a0, b0, acc0, 0, 0, 0);
      acc1 = __builtin_amdgcn_mfma_f32_16x16x32_bf16(a1, b1, acc1, 0, 0, 0);
    }
    f32x4 acc = acc0 + acc1;
    __syncthreads();
#pragma unroll
    for (int q = 0; q < 4; ++q)
      gates_s[(mt * 16 + (lane >> 4) * 4 + q) * 33 + nt * 16 + (lane & 15)] = acc[q];
    __syncthreads();

    // ---- elementwise gating: thread -> (batch b_, hidden j0+jj) ----
    asm volatile("s_waitcnt vmcnt(0)" ::: "memory");    // Gx ready (free if drained)
    float hn;
    {
      float sf = gates_s[b_ * 33 + jj]      + __half2float(__ushort_as_half((unsigned short)gxa)) + rb0;
      float si = gates_s[b_ * 33 + 8 + jj]  + __half2float(__ushort_as_half((unsigned short)gxb)) + rb1;
      float so = gates_s[b_ * 33 + 16 + jj] + __half2float(__ushort_as_half((unsigned short)gxc)) + rb2;
      float sc = gates_s[b_ * 33 + 24 + jj] + __half2float(__ushort_as_half((unsigned short)gxd)) + rb3;
      float gf = 1.f / (1.f + expf(-sf));
      float gi = 1.f / (1.f + expf(-si));
      float go = 1.f / (1.f + expf(-so));
      float cn = gf * c_reg + gi * tanhf(sc);
      hn = go * tanhf(cn);
      c_reg = cn;
      hlds[tid] = __half_as_ushort(__float2half(hn + 2.0f));   // fp16(h+2), never 0
    }
    float* outp = out + ((size_t)b_ * L_SZ + t) * H_SZ + j0 + jj;

    if (t < 511) {
      __syncthreads();                                  // hlds complete
      if (tid < 32) {                                   // fire-and-forget: 32 x 16B
        u32x4 v = *(u32x4*)(hlds + tid * 8);
        unsigned short* hp = hout + (size_t)tid * H_SZ + j0;
        asm volatile("global_store_dwordx4 %0, %1, off sc0 sc1"
                     :: "v"(hp), "v"(v) : "memory");
      }
      *outp = hn;                                       // cached, off critical path
      // no drain, no flag, no barrier - straight into next step's retry fetch
    } else {
      *outp = hn;
    }
  }
}

// ---- host launcher ----------------------------------------------------------

extern "C" void kernel_launch(void* const* d_in, const int* in_sizes, int n_in,
                              void* d_out, int out_size, void* d_ws, size_t ws_size,
                              hipStream_t stream) {
  const float* x = (const float*)d_in[0];
  const float* W = (const float*)d_in[1];
  const float* b = (const float*)d_in[2];
  char* ws = (char*)d_ws;
  __half* Gx           = (__half*)(ws + GX_OFF);
  unsigned short* xb   = (unsigned short*)(ws + XB_OFF);   // becomes h ring
  unsigned short* Wh   = (unsigned short*)(ws + WH_OFF);
  unsigned short* Wx   = (unsigned short*)(ws + WX_OFF);
  float* out = (float*)d_out;

  // prep: bf16 conversions
  k_convert_w<<<8192, 256, 0, stream>>>(W, Wh, Wx);
  k_convert_x<<<16384, 256, 0, stream>>>(x, xb);

  // input projection for all timesteps (consumes xb)
  k_xgemm<<<dim3(128, 32), 256, 0, stream>>>(xb, Wx, Gx);

  // zero ring slots 1..511 (xb dead after xgemm): 511*64KB = 8372224 dwords
  k_zero_wt<<<32704, 256, 0, stream>>>((unsigned*)(ws + XB_OFF + 65536), 8372224);

  // persistent recurrence (135936 B dynamic LDS > 64KB default -> raise cap)
  (void)hipFuncSetAttribute((const void*)k_lstm,
                            hipFuncAttributeMaxDynamicSharedMemorySize, 135936);
  k_lstm<<<128, 256, 135936, stream>>>(Wh, Gx, b, xb, out);
}

// Round 10
// 2163.144 us; speedup vs baseline: 1.7933x; 1.7933x over previous
//
#include <hip/hip_runtime.h>
#include <hip/hip_fp16.h>

// Problem sizes
#define B_SZ 32
#define L_SZ 512
#define D_SZ 1024
#define H_SZ 1024
#define NG   4096           // 4*H
#define M_SZ 16384          // B*L

typedef __attribute__((ext_vector_type(8))) short short8;
typedef __attribute__((ext_vector_type(4))) float f32x4;
typedef __attribute__((ext_vector_type(4))) unsigned u32x4;
typedef __attribute__((ext_vector_type(4))) unsigned short u16x4;

// Workspace layout (bytes). Total ~184.7 MB.
// XB region doubles as the h RING (512 slots x 64 KB = exactly 32 MiB) once
// k_xgemm has consumed the bf16 x data.
static const size_t GX_OFF  = 0;                  // Gx fp16: 16384*4096*2 = 134217728
static const size_t XB_OFF  = 134217728;          // x bf16 / h ring: 33554432
static const size_t WH_OFF  = 167772160;          // Wh bf16: 8388608
static const size_t WX_OFF  = 176160768;          // Wx bf16: 8388608
static const size_t FLG_OFF = 184680448;          // flags: 128 x 64B = 8192

__device__ __forceinline__ unsigned short f2bf(float f) {
  union { float f; unsigned u; } v; v.f = f;
  unsigned r = v.u + 0x7fffu + ((v.u >> 16) & 1u);
  return (unsigned short)(r >> 16);
}

__device__ __forceinline__ void gload_lds16(const void* g, void* l) {
  __builtin_amdgcn_global_load_lds(
      (const __attribute__((address_space(1))) unsigned*)g,
      (__attribute__((address_space(3))) unsigned*)l, 16, 0, 0);
}

// ---- prep kernels -----------------------------------------------------------

__global__ __launch_bounds__(256) void k_convert_w(const float* __restrict__ W,
                                                   unsigned short* __restrict__ Wh,
                                                   unsigned short* __restrict__ Wx) {
  int idx = blockIdx.x * 256 + threadIdx.x;          // 4096*2048/4 = 2097152 total
  f32x4 v = ((const f32x4*)W)[idx];
  u16x4 o;
#pragma unroll
  for (int e = 0; e < 4; ++e) o[e] = f2bf(v[e]);
  int n   = idx >> 9;                                // 512 float4 per 2048-col row
  int col = (idx & 511) * 4;
  if (col < 1024) *(u16x4*)(Wh + (size_t)n * 1024 + col)          = o;
  else            *(u16x4*)(Wx + (size_t)n * 1024 + (col - 1024)) = o;
}

// xb region later becomes the h ring, written sc0sc1 (write-through). xb is
// also stored write-through so NO dirty L2 line of this region can ever be
// written back late and clobber ring data.
__global__ __launch_bounds__(256) void k_convert_x(const float* __restrict__ x,
                                                   unsigned short* __restrict__ xb) {
  int idx = blockIdx.x * 256 + threadIdx.x;          // 16777216/4 = 4194304 total
  f32x4 v = ((const f32x4*)x)[idx];
  u16x4 o;
#pragma unroll
  for (int e = 0; e < 4; ++e) o[e] = f2bf(v[e]);
  unsigned long long val;
  __builtin_memcpy(&val, &o, 8);
  unsigned short* p = xb + (size_t)idx * 4;
  asm volatile("global_store_dwordx2 %0, %1, off sc0 sc1"
               :: "v"(p), "v"(val) : "memory");
}

__global__ __launch_bounds__(256) void k_zero_wt(unsigned* __restrict__ p, int n) {
  int i = blockIdx.x * 256 + threadIdx.x;
  unsigned z = 0u;
  if (i < n)
    asm volatile("global_store_dword %0, %1, off sc0 sc1"
                 :: "v"(p + i), "v"(z) : "memory");
}

// ---- x-projection GEMM: Gx[m][n] = sum_d x[m][d] * Wx[n][d] (fp16 out) ------

__global__ __launch_bounds__(256) void k_xgemm(const unsigned short* __restrict__ A,
                                               const unsigned short* __restrict__ Bw,
                                               __half* __restrict__ C) {
  __shared__ unsigned short sA[128 * 64];
  __shared__ unsigned short sB[128 * 64];
  const int m0 = blockIdx.x * 128;
  const int n0 = blockIdx.y * 128;
  const int tid = threadIdx.x;
  const int lane = tid & 63;
  const int w = tid >> 6;
  const int wm = w >> 1, wn = w & 1;
  f32x4 acc[4][4] = {};
  for (int k0 = 0; k0 < 1024; k0 += 64) {
#pragma unroll
    for (int it = 0; it < 4; ++it) {
      int chunk = it * 256 + w * 64 + lane;
      int row = chunk >> 3, kc = chunk & 7;
      gload_lds16(A + (size_t)(m0 + row) * 1024 + k0 + kc * 8,
                  (char*)sA + (size_t)(it * 256 + w * 64) * 16);
      gload_lds16(Bw + (size_t)(n0 + row) * 1024 + k0 + kc * 8,
                  (char*)sB + (size_t)(it * 256 + w * 64) * 16);
    }
    asm volatile("s_waitcnt vmcnt(0)" ::: "memory");
    __syncthreads();
#pragma unroll
    for (int ks = 0; ks < 2; ++ks) {
      short8 af[4], bfr[4];
#pragma unroll
      for (int i = 0; i < 4; ++i) {
        int arow = wm * 64 + i * 16 + (lane & 15);
        af[i] = *(const short8*)(sA + arow * 64 + ks * 32 + (lane >> 4) * 8);
      }
#pragma unroll
      for (int j = 0; j < 4; ++j) {
        int brow = wn * 64 + j * 16 + (lane & 15);
        bfr[j] = *(const short8*)(sB + brow * 64 + ks * 32 + (lane >> 4) * 8);
      }
#pragma unroll
      for (int i = 0; i < 4; ++i)
#pragma unroll
        for (int j = 0; j < 4; ++j)
          acc[i][j] = __builtin_amdgcn_mfma_f32_16x16x32_bf16(af[i], bfr[j], acc[i][j], 0, 0, 0);
    }
    __syncthreads();
  }
#pragma unroll
  for (int i = 0; i < 4; ++i)
#pragma unroll
    for (int j = 0; j < 4; ++j)
#pragma unroll
      for (int q = 0; q < 4; ++q) {
        int row = m0 + wm * 64 + i * 16 + (lane >> 4) * 4 + q;
        int col = n0 + wn * 64 + j * 16 + (lane & 15);
        C[(size_t)row * NG + col] = __float2half(acc[i][j][q]);
      }
}

// ---- persistent recurrent kernel -------------------------------------------
// 128 WGs x 256 threads (1 WG/CU, launch_bounds(256,1) -> 256 VGPR budget).
// WG wg owns hidden j0..j0+7 across all 4 gates (32 gate columns).
//
// K-SPLIT MFMA: wave wv owns K-slice [wv*256, wv*256+256) and computes ALL
// FOUR 16x16 quadrants of the 32x32 gates tile over its slice. Each K-chunk
// of the h tile (A) is read from LDS exactly ONCE per CU (16 b128/wave,
// 64/CU - was 256/CU), and the Wh B-fragments for the slice live in
// REGISTERS (16 frags = 64 VGPR, preloaded once from global). Partial sums
// are exchanged through fp32 part[4][32][36] in LDS and summed by the
// gating threads.
//
// RULE #18 GUARDS: every value produced by an inline-asm load and guarded by
// an inline-asm s_waitcnt gets a sched_barrier(0) right after the waitcnt -
// register-only consumers (cvt, gating math) are NOT ordered by the asm's
// "memory" clobber and hipcc can hoist them above the waitcnt (R8's failure).
//
// Cross-step h exchange (proven R4 structure, unchanged): 512-slot ring;
// producers store slot t+1 with sc0 sc1 (write-through to coherence point;
// vmcnt(0) ack precedes the per-WG flag). Consumers poll flags with sc0sc1,
// then read slot t with normal CACHED loads - safe because each slot line
// is written exactly once before its first read in this launch (kernel-
// start acquire fence drops stale clean copies from k_xgemm/prior replays).

__global__ __launch_bounds__(256, 1) void k_lstm(const unsigned short* __restrict__ Whg,
                                                 const __half* __restrict__ Gx,
                                                 const float* __restrict__ bias,
                                                 unsigned short* __restrict__ ring,
                                                 float* __restrict__ out,
                                                 unsigned* __restrict__ flags) {
  extern __shared__ char lds[];
  char* h_base  = lds;                                 // 65536 B swizzled [32][1024] bf16
  float* part   = (float*)(lds + 65536);               // [4][32][36] fp32 = 18432 B
  float* bias_s = (float*)(lds + 65536 + 18432);       // [32]
  unsigned short* hlds = (unsigned short*)(lds + 65536 + 18432 + 128); // [256]

  const int tid = threadIdx.x;
  const int lane = tid & 63;
  const int wv = tid >> 6;          // wave id = K-slice owner
  const int wg = blockIdx.x;
  const int j0 = wg * 8;

  // acquire: drop stale clean cached lines of the ring region before any
  // cached ring read in this launch.
  __builtin_amdgcn_fence(__ATOMIC_ACQUIRE, "agent");

  // ---- one-time: this wave's K-slice of Wh -> registers (16 frags) ----
  short8 bfrag[2][8];
#pragma unroll
  for (int ntx = 0; ntx < 2; ++ntx) {
#pragma unroll
    for (int ks = 0; ks < 8; ++ks) {
      int br = ntx * 16 + (lane & 15);                 // local gate col
      const unsigned short* src = Whg
          + (size_t)((br >> 3) * 1024 + j0 + (br & 7)) * 1024
          + wv * 256 + ks * 32 + (lane >> 4) * 8;
      bfrag[ntx][ks] = *(const short8*)src;
    }
  }
  if (tid < 32) bias_s[tid] = bias[(tid >> 3) * 1024 + j0 + (tid & 7)];
  __syncthreads();

  const int row0 = lane & 15;                          // A rows; second half +16
  const char* aB0 = h_base + row0 * 2048;
  const char* aB1 = h_base + (16 + row0) * 2048;
  const int kslot = (lane >> 4) * 16;
  const int aswz = (row0 & 7) << 4;                    // same for row0+16
  const int kbyte0 = wv * 512;                         // K-slice byte offset in a row
  const int b_ = tid >> 3, jj = tid & 7;
  const float rb0 = bias_s[jj], rb1 = bias_s[8 + jj];
  const float rb2 = bias_s[16 + jj], rb3 = bias_s[24 + jj];
  float c_reg = 0.f;                                   // cell state (thread-private)

  // poll pointers (wave 0): lane covers flags[2*lane], flags[2*lane+1] (64B-spread)
  const unsigned* fp0 = flags + (size_t)(2 * tid) * 16;
  const unsigned* fp1 = flags + (size_t)(2 * tid + 1) * 16;

  for (int t = 0; t < 512; ++t) {
    const char* hin = (const char*)ring + (size_t)t * 65536;   // slot t
    unsigned short* hout = ring + (size_t)(t + 1) * 32768;     // slot t+1

    // ---- issue VMEM in fixed order: 16 h loads (CACHED), then 4 Gx loads ----
    u32x4 hz = {0u, 0u, 0u, 0u};
    u32x4 h0=hz,h1=hz,h2=hz,h3=hz,h4=hz,h5=hz,h6=hz,h7=hz,
          h8=hz,h9=hz,h10=hz,h11=hz,h12=hz,h13=hz,h14=hz,h15=hz;
    if (t) {
#define HLD(r, it) asm volatile("global_load_dwordx4 %0, %1, off" \
      : "=v"(r) : "v"(hin + (size_t)((it) * 256 + tid) * 16) : "memory")
      HLD(h0,0); HLD(h1,1); HLD(h2,2); HLD(h3,3);
      HLD(h4,4); HLD(h5,5); HLD(h6,6); HLD(h7,7);
      HLD(h8,8); HLD(h9,9); HLD(h10,10); HLD(h11,11);
      HLD(h12,12); HLD(h13,13); HLD(h14,14); HLD(h15,15);
#undef HLD
    }
    const char* gxp = (const char*)(Gx + ((size_t)(b_ * L_SZ + t)) * NG + j0 + jj);
    unsigned gxa, gxb, gxc, gxd;
    asm volatile("global_load_ushort %0, %1, off" : "=v"(gxa) : "v"(gxp)        : "memory");
    asm volatile("global_load_ushort %0, %1, off" : "=v"(gxb) : "v"(gxp + 2048) : "memory");
    asm volatile("global_load_ushort %0, %1, off" : "=v"(gxc) : "v"(gxp + 4096) : "memory");
    asm volatile("global_load_ushort %0, %1, off" : "=v"(gxd) : "v"(gxp + 6144) : "memory");

    // ---- stage h into swizzled LDS with counted waits ----
    // (a lingering out-store from step t-1 is always the OLDEST outstanding
    //  op, so the counted waits below still guarantee h chunks have landed)
#define HWR(r, it) { int i_ = (it) * 256 + tid; int bb_ = i_ >> 7, kc_ = i_ & 127; \
      *(u32x4*)(h_base + bb_ * 2048 + ((kc_ * 16) ^ ((bb_ & 7) << 4))) = r; }
    asm volatile("s_waitcnt vmcnt(12)" ::: "memory");   // h0..h7 landed
    __builtin_amdgcn_sched_barrier(0);                  // rule #18 fence
    HWR(h0,0); HWR(h1,1); HWR(h2,2); HWR(h3,3);
    HWR(h4,4); HWR(h5,5); HWR(h6,6); HWR(h7,7);
    asm volatile("s_waitcnt vmcnt(4)" ::: "memory");    // h8..h15 landed (Gx in flight)
    __builtin_amdgcn_sched_barrier(0);                  // rule #18 fence
    HWR(h8,8); HWR(h9,9); HWR(h10,10); HWR(h11,11);
    HWR(h12,12); HWR(h13,13); HWR(h14,14); HWR(h15,15);
#undef HWR
    __syncthreads();

    // ---- K-split MFMA: all 4 quadrants over this wave's K-slice ----
    f32x4 acc00 = {0.f,0.f,0.f,0.f}, acc01 = {0.f,0.f,0.f,0.f};
    f32x4 acc10 = {0.f,0.f,0.f,0.f}, acc11 = {0.f,0.f,0.f,0.f};
#pragma unroll
    for (int ks = 0; ks < 8; ++ks) {
      int kb = kbyte0 + ks * 64 + kslot;
      short8 a0 = *(const short8*)(aB0 + (kb ^ aswz));
      short8 a1 = *(const short8*)(aB1 + (kb ^ aswz));
      acc00 = __builtin_amdgcn_mfma_f32_16x16x32_bf16(a0, bfrag[0][ks], acc00, 0, 0, 0);
      acc01 = __builtin_amdgcn_mfma_f32_16x16x32_bf16(a0, bfrag[1][ks], acc01, 0, 0, 0);
      acc10 = __builtin_amdgcn_mfma_f32_16x16x32_bf16(a1, bfrag[0][ks], acc10, 0, 0, 0);
      acc11 = __builtin_amdgcn_mfma_f32_16x16x32_bf16(a1, bfrag[1][ks], acc11, 0, 0, 0);
    }
    // partial store: part[wv][row][col], stride 36
    {
      float* pw = part + wv * 1152;
      int r0 = (lane >> 4) * 4, cA = lane & 15;
#pragma unroll
      for (int q = 0; q < 4; ++q) {
        pw[(r0 + q) * 36 + cA]           = acc00[q];
        pw[(r0 + q) * 36 + 16 + cA]      = acc01[q];
        pw[(16 + r0 + q) * 36 + cA]      = acc10[q];
        pw[(16 + r0 + q) * 36 + 16 + cA] = acc11[q];
      }
    }
    __syncthreads();

    // ---- gating: sum 4 partials, thread -> (batch b_, hidden j0+jj) ----
    float s0 = 0.f, s1 = 0.f, s2 = 0.f, s3 = 0.f;
#pragma unroll
    for (int p = 0; p < 4; ++p) {
      const float* pp = part + p * 1152 + b_ * 36 + jj;
      s0 += pp[0]; s1 += pp[8]; s2 += pp[16]; s3 += pp[24];
    }
    asm volatile("s_waitcnt vmcnt(0)" ::: "memory");    // Gx ready
    __builtin_amdgcn_sched_barrier(0);                  // rule #18 fence (gx consumers)
    float hn;
    {
      float sf = s0 + __half2float(__ushort_as_half((unsigned short)gxa)) + rb0;
      float si = s1 + __half2float(__ushort_as_half((unsigned short)gxb)) + rb1;
      float so = s2 + __half2float(__ushort_as_half((unsigned short)gxc)) + rb2;
      float sc = s3 + __half2float(__ushort_as_half((unsigned short)gxd)) + rb3;
      float gf = 1.f / (1.f + expf(-sf));
      float gi = 1.f / (1.f + expf(-si));
      float go = 1.f / (1.f + expf(-so));
      float cn = gf * c_reg + gi * tanhf(sc);
      hn = go * tanhf(cn);
      c_reg = cn;
      hlds[tid] = f2bf(hn);                             // hlds[b_*8+jj] == hlds[tid]
    }
    float* outp = out + ((size_t)b_ * L_SZ + t) * H_SZ + j0 + jj;

    if (t < 511) {
      __syncthreads();                                  // hlds complete
      if (tid < 32) {                                   // packed h store: 32 x 16B
        u32x4 v = *(u32x4*)(hlds + tid * 8);
        unsigned short* hp = hout + (size_t)tid * H_SZ + j0;
        asm volatile("global_store_dwordx4 %0, %1, off sc0 sc1"
                     :: "v"(hp), "v"(v) : "memory");
      }
      // all h stores are wave 0's -> wave 0's own drain suffices for the flag
      asm volatile("s_waitcnt vmcnt(0)" ::: "memory");  // h stores at coherence point
      if (tid == 0) {                                   // parallel-store flag barrier
        unsigned fv = (unsigned)(t + 1);
        const unsigned* myf = flags + (size_t)wg * 16;
        asm volatile("global_store_dword %0, %1, off sc0 sc1"
                     :: "v"(myf), "v"(fv) : "memory");
      }
      *outp = hn;                                       // cached, off critical path
      if (tid < 64) {                                   // wave 0 polls all 128 flags
        unsigned fa, fb;
        do {
          asm volatile("global_load_dword %0, %2, off sc0 sc1\n\t"
                       "global_load_dword %1, %3, off sc0 sc1\n\t"
                       "s_waitcnt vmcnt(0)"
                       : "=v"(fa), "=v"(fb) : "v"(fp0), "v"(fp1) : "memory");
        } while (!__all(fa > (unsigned)t && fb > (unsigned)t));
      }
      __syncthreads();                                  // all producers done
    } else {
      *outp = hn;
    }
  }
}

// ---- host launcher ----------------------------------------------------------

extern "C" void kernel_launch(void* const* d_in, const int* in_sizes, int n_in,
                              void* d_out, int out_size, void* d_ws, size_t ws_size,
                              hipStream_t stream) {
  const float* x = (const float*)d_in[0];
  const float* W = (const float*)d_in[1];
  const float* b = (const float*)d_in[2];
  char* ws = (char*)d_ws;
  __half* Gx           = (__half*)(ws + GX_OFF);
  unsigned short* xb   = (unsigned short*)(ws + XB_OFF);   // becomes h ring
  unsigned short* Wh   = (unsigned short*)(ws + WH_OFF);
  unsigned short* Wx   = (unsigned short*)(ws + WX_OFF);
  unsigned* flags      = (unsigned*)(ws + FLG_OFF);
  float* out = (float*)d_out;

  // prep: bf16 conversions + zero flags (re-zeroed every call -> deterministic)
  k_convert_w<<<8192, 256, 0, stream>>>(W, Wh, Wx);
  k_convert_x<<<16384, 256, 0, stream>>>(x, xb);
  k_zero_wt<<<8, 256, 0, stream>>>(flags, 8192 / 4);

  // input projection for all timesteps (consumes xb)
  k_xgemm<<<dim3(128, 32), 256, 0, stream>>>(xb, Wx, Gx);

  // persistent recurrence (84608 B dynamic LDS > 64KB default -> raise cap)
  (void)hipFuncSetAttribute((const void*)k_lstm,
                            hipFuncAttributeMaxDynamicSharedMemorySize, 84608);
  k_lstm<<<128, 256, 84608, stream>>>(Wh, Gx, b, xb, out, flags);
}